// Round 9
// baseline (253.127 us; speedup 1.0000x reference)
//
#include <hip/hip_runtime.h>
#include <cmath>

#define BB  1024
#define TT  128
#define HH1 512
#define HH2 256
#define CC  18

// d_ws layout (byte offsets)
#define WS_DIG   0ull             // W2 digits: 8x4x16x2x32x16 i8 = 512 KB
#define WS_W3D   524288ull        // W3 digits LDS image: 32 KB
#define WS_MASK  557056ull        // s1 masks[t][row][8 u64] = 8 MB
#define WS_MASK2 8945664ull       // s2 masks[t][row][8 u32] = 4 MB
#define WS_D3    13139968ull      // D3[t][row][c<18] fp32 = 9.4 MB (end ~22.6 MB)

typedef int  v4i  __attribute__((ext_vector_type(4)));
typedef int  v16i __attribute__((ext_vector_type(16)));
typedef unsigned long long ull;

__device__ __forceinline__ v4i expand_bits(unsigned bits) {
  v4i a;
  a.x = (int)((( bits        & 15u) * 0x204081u) & 0x01010101u);
  a.y = (int)((((bits >>  4) & 15u) * 0x204081u) & 0x01010101u);
  a.z = (int)((((bits >>  8) & 15u) * 0x204081u) & 0x01010101u);
  a.w = (int)((((bits >> 12) & 15u) * 0x204081u) & 0x01010101u);
  return a;
}

// ---- merged front end: W2 digits | W3 digits | bit-exact layer-1 masks.
// grid 3200 = 2048 (prep_digits) + 128 (prep_w3dig) + 1024 (phase_s1).
__global__ __launch_bounds__(256) void phase_front(const float* __restrict__ W2,
    const float* __restrict__ W3, const float* __restrict__ x,
    const float* __restrict__ W1, const float* __restrict__ b1,
    signed char* __restrict__ dig, signed char* __restrict__ w3d,
    ull* __restrict__ masks)
{
  const int blk = blockIdx.x, tid = threadIdx.x;
  if (blk < 2048) {
    // W2 -> 4 signed-i8 digit planes of llrint(w*2^32), layout
    // [stripe(8)][d(4)][s(16)][h(2)][n(32)][j(16)]; h1=s*32+h*16+j, h2=stripe*32+n
    int i = blk * 256 + tid;                       // [0, 524288)
    int j = i & 15, n = (i >> 4) & 31, h = (i >> 9) & 1;
    int s = (i >> 10) & 15, d = (i >> 14) & 3, st = i >> 16;
    int h1 = s * 32 + h * 16 + j;
    int h2 = st * 32 + n;
    float w = W2[h2 * HH1 + h1];
    long long ll = llrint((double)w * 4294967296.0);
    int v = (int)ll;
    signed char d0 = (signed char)(v & 255); v = (v - d0) >> 8;
    signed char d1 = (signed char)(v & 255); v = (v - d1) >> 8;
    signed char d2 = (signed char)(v & 255); v = (v - d2) >> 8;
    signed char d3 = (signed char)v;
    dig[i] = (d == 0) ? d0 : (d == 1) ? d1 : (d == 2) ? d2 : d3;
  } else if (blk < 2176) {
    // W3 digits, LDS image [d(4)][c8(8)][h(2)][col(32)][j(16)], 32 KB
    int i = (blk - 2048) * 256 + tid;              // [0, 32768)
    int j = i & 15, col = (i >> 4) & 31, h = (i >> 9) & 1;
    int c8 = (i >> 10) & 7, d = (i >> 13) & 3;
    int h2 = c8 * 32 + h * 16 + j;
    float w = (col < CC) ? W3[col * HH2 + h2] : 0.0f;
    long long ll = llrint((double)w * 4294967296.0);
    int v = (int)ll;
    signed char d0 = (signed char)(v & 255); v = (v - d0) >> 8;
    signed char d1 = (signed char)(v & 255); v = (v - d1) >> 8;
    signed char d2 = (signed char)(v & 255); v = (v - d2) >> 8;
    signed char d3 = (signed char)v;
    w3d[i] = (d == 0) ? d0 : (d == 1) ? d1 : (d == 2) ? d2 : d3;
  } else {
    // bit-exact layer 1 (mul-rn, add-rn, add-rn), one block per row
    __shared__ float xrow[TT];
    const int row = blk - 2176, wv = tid >> 6, lane = tid & 63;
    for (int i = tid; i < TT; i += 256) xrow[i] = x[row * TT + i];
    const float w1a = W1[tid], w1b = W1[tid + 256];
    const float b1a = b1[tid], b1b = b1[tid + 256];
    float v1a = 0.f, v1b = 0.f;
    __syncthreads();
    for (int t = 0; t < TT; ++t) {
      float xt = xrow[t];
      float iA = __fadd_rn(__fmul_rn(xt, w1a), b1a);
      v1a = __fadd_rn(v1a, iA);
      bool sA = (v1a >= 1.0f);  v1a = sA ? (v1a - 1.0f) : v1a;
      float iB = __fadd_rn(__fmul_rn(xt, w1b), b1b);
      v1b = __fadd_rn(v1b, iB);
      bool sB = (v1b >= 1.0f);  v1b = sB ? (v1b - 1.0f) : v1b;
      ull mA = __ballot(sA);
      ull mB = __ballot(sB);
      if (lane == 0) {
        ull* p = masks + ((size_t)t * BB + row) * 8;
        p[wv] = mA; p[4 + wv] = mB;
      }
    }
  }
}

// ---- fused layer 2: producer-consumer, 768 threads = 12 waves.
// Waves 0-7: exact i8-MFMA GEMM, wave wv owns t = c*8+wv (full K=512, 4 digit
// planes, next-chunk mask prefetch in regs) -> d2buf[c&1].
// Waves 8-11: v2-scan of chunk c-1 from d2buf[1-(c&1)] -> s2 ballot masks.
// bid swizzle: stripe-siblings (identical masks) share an XCD (bid%8 const).
__global__ __launch_bounds__(768) void phase_gemmscan(
    const signed char* __restrict__ Bd, const ull* __restrict__ masks,
    const float* __restrict__ b2, unsigned* __restrict__ masks2)
{
  __shared__ __align__(16) signed char Bl[65536];
  __shared__ float d2buf[2][8 * 1024];             // 2 x 32 KB

  const int bid = blockIdx.x;
  const int rowtile = bid & 31, stripe = bid >> 5; // stripe-siblings: same XCD
  const int tid = threadIdx.x, lane = tid & 63, wv = tid >> 6;
  const int half = lane >> 5;

  {
    const uint4* src = (const uint4*)(Bd + (size_t)stripe * 65536);
    uint4* dst = (uint4*)Bl;
    for (int i = tid; i < 4096; i += 768) dst[i] = src[i];
  }

  // GEMM-wave constants (wv < 8)
  const int arow = rowtile * 32 + (lane & 31);
  const int hsh  = half * 16;
  const signed char* bbase = Bl + half * 512 + (lane & 31) * 16;

  // scan-wave constants (wv >= 8)
  const int stid = tid - 512;                      // 0..255 for waves 8-11
  const int scol = stid & 31, sgrp = stid >> 5;    // col, 4-row group
  float v2[4] = {0.f, 0.f, 0.f, 0.f};
  float b2r = 0.f;
  if (wv >= 8) b2r = b2[stripe * 32 + scol];

  // prefetch chunk-0 masks (t = wv)
  ull pm[8];
  if (wv < 8) {
    const ull* p = masks + ((size_t)wv * BB + arow) * 8;
#pragma unroll
    for (int k = 0; k < 8; ++k) pm[k] = p[k];
  }

  __syncthreads();                                 // Bl ready

  for (int c = 0; c < 17; ++c) {
    if (wv < 8 && c < 16) {
      ull wA[8];
#pragma unroll
      for (int k = 0; k < 8; ++k) wA[k] = pm[k];
      // issue next-chunk mask loads now; consumed after the MFMA loop ends
      const int cn = (c + 1 < 16) ? c + 1 : 15;
      { const ull* p = masks + ((size_t)(cn * 8 + wv) * BB + arow) * 8;
#pragma unroll
        for (int k = 0; k < 8; ++k) pm[k] = p[k]; }

      v16i acc[4];
#pragma unroll
      for (int d = 0; d < 4; ++d) acc[d] = (v16i){0,0,0,0,0,0,0,0,0,0,0,0,0,0,0,0};
#pragma unroll
      for (int s = 0; s < 16; ++s) {
        v4i q0 = *(const v4i*)(bbase + (0 * 16 + s) * 1024);
        v4i q1 = *(const v4i*)(bbase + (1 * 16 + s) * 1024);
        v4i q2 = *(const v4i*)(bbase + (2 * 16 + s) * 1024);
        v4i q3 = *(const v4i*)(bbase + (3 * 16 + s) * 1024);
        unsigned shift = ((s & 1) << 5) + hsh;
        v4i a = expand_bits((unsigned)(wA[s >> 1] >> shift) & 0xFFFFu);
        acc[0] = __builtin_amdgcn_mfma_i32_32x32x32_i8(a, q0, acc[0], 0, 0, 0);
        acc[1] = __builtin_amdgcn_mfma_i32_32x32x32_i8(a, q1, acc[1], 0, 0, 0);
        acc[2] = __builtin_amdgcn_mfma_i32_32x32x32_i8(a, q2, acc[2], 0, 0, 0);
        acc[3] = __builtin_amdgcn_mfma_i32_32x32x32_i8(a, q3, acc[3], 0, 0, 0);
      }
      // exact digit fold -> one f32 rounding (bit-identical to R4 path)
      float* buf = d2buf[c & 1];
#pragma unroll
      for (int r = 0; r < 16; ++r) {
        int slo = acc[0][r] + (acc[1][r] << 8);    // |.| < 2^25, exact i32
        int shi = acc[2][r] + (acc[3][r] << 8);
        double ss = fma((double)shi, 65536.0, (double)slo);   // exact
        float dA = (float)(ss * 0x1p-32);                     // one rounding
        int rowl = (r & 3) + 8 * (r >> 2) + 4 * half;
        buf[wv * 1024 + rowl * 32 + (lane & 31)] = dA;
      }
    }
    if (wv >= 8 && c > 0) {
      const int tb = (c - 1) * 8;
      const float* buf = d2buf[(c - 1) & 1];
      for (int tl = 0; tl < 8; ++tl) {
        const int t = tb + tl;
#pragma unroll
        for (int q = 0; q < 4; ++q) {
          float d2 = buf[tl * 1024 + (sgrp * 4 + q) * 32 + scol];
          float i2 = __fadd_rn(d2, b2r);
          v2[q] = __fadd_rn(v2[q], i2);
          bool s2 = (v2[q] >= 1.0f);
          v2[q] = s2 ? (v2[q] - 1.0f) : v2[q];
          ull m = __ballot(s2);                    // lo32: even sgrp, hi32: odd
          if (lane == 0)
            masks2[((size_t)t * BB + rowtile * 32 + sgrp * 4 + q) * 8 + stripe]
                = (unsigned)m;
          else if (lane == 32)
            masks2[((size_t)t * BB + rowtile * 32 + sgrp * 4 + q) * 8 + stripe]
                = (unsigned)(m >> 32);
        }
      }
    }
    __syncthreads();
  }
}

// ---- layer 3: D3[t] = S2[t] @ W3^T, exact i8 MFMA. Block: 32 rows x 4 t.
__global__ __launch_bounds__(256) void phase_l3(const signed char* __restrict__ W3d,
    const unsigned* __restrict__ masks2, float* __restrict__ D3)
{
  __shared__ __align__(16) signed char Bl[32768];
  const int bid = blockIdx.x;
  const int rowtile = bid & 31, tgrp = bid >> 5;
  const int tid = threadIdx.x, lane = tid & 63, wv = tid >> 6;
  const int half = lane >> 5;
  const int t = tgrp * 4 + wv;
  const int row = rowtile * 32 + (lane & 31);

  {
    const uint4* src = (const uint4*)W3d;
    uint4* dst = (uint4*)Bl;
#pragma unroll
    for (int i = 0; i < 8; ++i) dst[tid + 256 * i] = src[tid + 256 * i];
  }

  unsigned words[8];
  {
    const unsigned* mp = masks2 + ((size_t)t * BB + row) * 8;
#pragma unroll
    for (int k = 0; k < 8; ++k) words[k] = mp[k];
  }
  __syncthreads();

  const signed char* bbase = Bl + half * 512 + (lane & 31) * 16;
  v16i acc[4];
#pragma unroll
  for (int d = 0; d < 4; ++d) acc[d] = (v16i){0,0,0,0,0,0,0,0,0,0,0,0,0,0,0,0};

#pragma unroll
  for (int c8 = 0; c8 < 8; ++c8) {
    v4i a = expand_bits((words[c8] >> (half * 16)) & 0xFFFFu);
#pragma unroll
    for (int d = 0; d < 4; ++d) {
      v4i b = *(const v4i*)(bbase + ((d * 8 + c8) * 2) * 512);
      acc[d] = __builtin_amdgcn_mfma_i32_32x32x32_i8(a, b, acc[d], 0, 0, 0);
    }
  }

  const int col = lane & 31;
#pragma unroll
  for (int r = 0; r < 16; ++r) {
    int slo = acc[0][r] + (acc[1][r] << 8);
    int shi = acc[2][r] + (acc[3][r] << 8);
    double ss = fma((double)shi, 65536.0, (double)slo);
    float d3v = (float)(ss * 0x1p-32);
    int rowl = (r & 3) + 8 * (r >> 2) + 4 * half;
    int grow = rowtile * 32 + rowl;
    if (col < CC) D3[((size_t)t * BB + grow) * CC + col] = d3v;
  }
}

// ---- v3/acc scan + output. thread=(row,c); 4-deep prefetch ring; grid 72.
__global__ __launch_bounds__(256) void phase_v3(const float* __restrict__ D3,
    const float* __restrict__ b3, float* __restrict__ out)
{
  int g = blockIdx.x * 256 + threadIdx.x;         // [0, 18432)
  int row = g / CC, c = g - row * CC;
  const float b3r = b3[c];
  float v3 = 0.f, acc = 0.f;
  float buf[4];
#pragma unroll
  for (int p = 0; p < 4; ++p) buf[p] = D3[(size_t)p * (BB * CC) + g];
  for (int t = 0; t < TT; ++t) {
    float d3 = buf[t & 3];
    if (t + 4 < TT) buf[t & 3] = D3[(size_t)(t + 4) * (BB * CC) + g];
    float i3 = __fadd_rn(d3, b3r);
    v3 = __fadd_rn(v3, i3);
    bool s3 = (v3 >= 1.0f);  v3 = s3 ? (v3 - 1.0f) : v3;
    acc = __fadd_rn(acc, s3 ? 1.0f : 0.0f);
  }
  out[g] = acc * (1.0f / TT);
}

extern "C" void kernel_launch(void* const* d_in, const int* in_sizes, int n_in,
                              void* d_out, int out_size, void* d_ws, size_t ws_size,
                              hipStream_t stream)
{
  (void)in_sizes; (void)n_in; (void)out_size; (void)ws_size;
  const float* x  = (const float*)d_in[0];
  const float* W1 = (const float*)d_in[1];
  const float* b1 = (const float*)d_in[2];
  const float* W2 = (const float*)d_in[3];
  const float* b2 = (const float*)d_in[4];
  const float* W3 = (const float*)d_in[5];
  const float* b3 = (const float*)d_in[6];
  // d_in[7] = repeat (structurally 1 for this problem shape)
  float* out = (float*)d_out;
  char*  ws  = (char*)d_ws;

  signed char* dig    = (signed char*)(ws + WS_DIG);
  signed char* w3dig  = (signed char*)(ws + WS_W3D);
  ull*         masks  = (ull*)(ws + WS_MASK);
  unsigned*    masks2 = (unsigned*)(ws + WS_MASK2);
  float*       D3     = (float*)(ws + WS_D3);

  phase_front<<<3200, 256, 0, stream>>>(W2, W3, x, W1, b1, dig, w3dig, masks);
  phase_gemmscan<<<256, 768, 0, stream>>>(dig, masks, b2, masks2);
  phase_l3<<<1024, 256, 0, stream>>>(w3dig, masks2, D3);
  phase_v3<<<72, 256, 0, stream>>>(D3, b3, out);
}